// Round 6
// baseline (333.859 us; speedup 1.0000x reference)
//
#include <hip/hip_runtime.h>
#include <math.h>

#define DFEAT 128
#define HDIM 256
#define KSROWS 192

typedef __attribute__((ext_vector_type(8))) short short8b;   // 8 bf16
typedef __attribute__((ext_vector_type(4))) short short4b;   // 4 bf16
typedef __attribute__((ext_vector_type(4))) float f32x4;

__device__ inline short f2bf(float f) {
    union { float f; unsigned u; } v; v.f = f;
    unsigned r = (v.u + 0x7fff + ((v.u >> 16) & 1)) >> 16;   // RNE
    return (short)r;
}
__device__ inline float bf2f(short s) {
    union { unsigned u; float f; } v; v.u = ((unsigned)(unsigned short)s) << 16;
    return v.f;
}
// wave-uniform broadcast from a lane (VALU pipe, not LDS)
__device__ inline float rdlane(float v, int l) {
    return __int_as_float(__builtin_amdgcn_readlane(__float_as_int(v), l));
}
__device__ __forceinline__ int swz(int row) { return ((row >> 4) & 3) << 3; }

// ---------------------------------------------------------------------------
// k_prep: fused {batch offsets, degree histogram, weight cast, x cast->U}.
// Sections by blockIdx: [0]=offsets | [1,1+hb)=hist | castx | castw.
// ---------------------------------------------------------------------------
__global__ __launch_bounds__(256) void k_prep(
    const int* __restrict__ batch1, const int* __restrict__ batch2,
    const int* __restrict__ ei1, const int* __restrict__ ei2,
    const float* __restrict__ x1, const float* __restrict__ x2,
    const float* __restrict__ msg_W1, const float* __restrict__ msg_b1,
    const float* __restrict__ msg_W2, const float* __restrict__ upd_W1,
    const float* __restrict__ upd_W2,
    int N, int E,
    int* __restrict__ offs1, int* __restrict__ offs2,
    int* __restrict__ deg1, int* __restrict__ deg2,
    short* __restrict__ U1, short* __restrict__ U2,
    short* __restrict__ WpqT, float* __restrict__ bias_pq,
    short* __restrict__ WmsgT, short* __restrict__ Wu1T, short* __restrict__ Wu2T)
{
    int hb = (2 * E + 255) >> 8;
    int xb = N >> 2;                 // castx blocks: 2 graphs * N*32 threads
    int bid = blockIdx.x;
    if (bid == 0) {                  // batch segment offsets (binary search)
        int t = threadIdx.x;
        if (t < 130) {
            const int* batch = (t < 65) ? batch1 : batch2;
            int b = (t < 65) ? t : t - 65;
            int lo = 0, hi = N;
            while (lo < hi) { int mid = (lo + hi) >> 1; if (batch[mid] < b) lo = mid + 1; else hi = mid; }
            if (t < 65) offs1[b] = lo; else offs2[b] = lo;
        }
        return;
    }
    bid -= 1;
    if (bid < hb) {                  // degree histogram
        int t = bid * 256 + threadIdx.x;
        if (t < E) atomicAdd(deg1 + ei1[t], 1);
        else if (t < 2 * E) atomicAdd(deg2 + ei2[t - E], 1);
        return;
    }
    bid -= hb;
    if (bid < xb) {                  // x -> bf16 into U cols 384..511
        int t = bid * 256 + threadIdx.x;
        int per = N * 32;
        const float* x; short* U;
        if (t < per) { x = x1; U = U1; } else { x = x2; U = U2; t -= per; }
        int row = t >> 5, i4 = (t & 31) * 4;
        float4 v = *(const float4*)&x[(size_t)row * DFEAT + i4];
        short4b s; s.x = f2bf(v.x); s.y = f2bf(v.y); s.z = f2bf(v.z); s.w = f2bf(v.w);
        *(short4b*)&U[(size_t)row * 512 + 384 + i4] = s;
        return;
    }
    bid -= xb;
    {                                // weight casts (295424 threads exactly)
        int t = bid * 256 + threadIdx.x;
        if (t < 65536) {             // WpqT[512][128]
            int j = t >> 7, k = t & 127;
            float v = (j < 256) ? msg_W1[(size_t)k * 256 + j]
                                : msg_W1[(size_t)(128 + k) * 256 + (j - 256)];
            WpqT[t] = f2bf(v);
            return;
        }
        t -= 65536;
        if (t < 512) { bias_pq[t] = (t < 256) ? msg_b1[t] : 0.f; return; }
        t -= 512;
        if (t < 65536) {             // WmsgT[256][256]
            int j = t >> 8, k = t & 255;
            WmsgT[t] = f2bf(msg_W2[(size_t)k * 256 + j]);
            return;
        }
        t -= 65536;
        if (t < 131072) {            // Wu1T[256][512]
            int j = t >> 9, k = t & 511;
            Wu1T[t] = f2bf(upd_W1[(size_t)k * 256 + j]);
            return;
        }
        t -= 131072;
        if (t < 32768) {             // Wu2T[128][256]
            int j = t >> 8, k = t & 255;
            Wu2T[t] = f2bf(upd_W2[(size_t)k * 128 + j]);
        }
    }
}

// ---------------------------------------------------------------------------
// CSR build: scan + scatter (hist lives in k_prep).
// ---------------------------------------------------------------------------
__global__ __launch_bounds__(256) void k_scan(const int* __restrict__ deg1,
                                              const int* __restrict__ deg2, int N,
                                              int* __restrict__ offs1, int* __restrict__ cur1,
                                              int* __restrict__ offs2, int* __restrict__ cur2) {
    const int* deg = blockIdx.x ? deg2 : deg1;
    int* offs = blockIdx.x ? offs2 : offs1;
    int* cur  = blockIdx.x ? cur2  : cur1;
    int t = threadIdx.x;
    int base = t * 32;
    int vals[32];
    int run = 0;
    #pragma unroll
    for (int i = 0; i < 32; ++i) { vals[i] = run; run += deg[base + i]; }
    __shared__ int tot[256];
    tot[t] = run;
    __syncthreads();
    for (int off = 1; off < 256; off <<= 1) {
        int v = (t >= off) ? tot[t - off] : 0;
        __syncthreads();
        tot[t] += v;
        __syncthreads();
    }
    int prefix = (t == 0) ? 0 : tot[t - 1];
    #pragma unroll
    for (int i = 0; i < 32; ++i) {
        int o = prefix + vals[i];
        offs[base + i] = o;
        cur[base + i] = o;
    }
    if (t == 255) offs[N] = tot[255];
}

__global__ __launch_bounds__(256) void k_scatter(const int* __restrict__ ei1,
                                                 const int* __restrict__ ei2, int E,
                                                 int* __restrict__ cur1, int* __restrict__ srcb1,
                                                 int* __restrict__ cur2, int* __restrict__ srcb2) {
    int t = blockIdx.x * 256 + threadIdx.x;
    if (t < E) {
        int tgt = ei1[t], src = ei1[E + t];
        srcb1[atomicAdd(cur1 + tgt, 1)] = src;
    } else if (t < 2 * E) {
        int e = t - E;
        int tgt = ei2[e], src = ei2[E + e];
        srcb2[atomicAdd(cur2 + tgt, 1)] = src;
    }
}

// ---------------------------------------------------------------------------
// MFMA GEMM: PQ_bf16[N][512] = x_bf(U cols 384..511) @ Wpq + bias.
// ---------------------------------------------------------------------------
__global__ __launch_bounds__(256) void k_pq_mfma(const short* __restrict__ U1,
                                                 const short* __restrict__ U2,
                                                 const short* __restrict__ WpqT,
                                                 const float* __restrict__ bias,
                                                 short* __restrict__ PQ1,
                                                 short* __restrict__ PQ2, int nblk) {
    int blk = blockIdx.x;
    const short* A; short* C;
    if (blk < nblk) { A = U1; C = PQ1; } else { A = U2; C = PQ2; blk -= nblk; }
    int w = threadIdx.x >> 6, l = threadIdx.x & 63;
    int row0 = blk * 32 + (w & 1) * 16;
    int ct0 = (w >> 1) * 16;
    int lm = l & 15, kg = (l >> 4) * 8;
    const short* Ar = A + (size_t)(row0 + lm) * 512 + 384 + kg;
    short8b a[4];
    #pragma unroll
    for (int ks = 0; ks < 4; ++ks) a[ks] = *(const short8b*)(Ar + ks * 32);
    for (int ct = ct0; ct < ct0 + 16; ++ct) {
        f32x4 acc = {0.f, 0.f, 0.f, 0.f};
        const short* Br = WpqT + (size_t)(ct * 16 + lm) * 128 + kg;
        #pragma unroll
        for (int ks = 0; ks < 4; ++ks) {
            short8b b = *(const short8b*)(Br + ks * 32);
            acc = __builtin_amdgcn_mfma_f32_16x16x32_bf16(a[ks], b, acc, 0, 0, 0);
        }
        int col = ct * 16 + lm;
        float bv = bias[col];
        #pragma unroll
        for (int j = 0; j < 4; ++j) {
            int r = row0 + (l >> 4) * 4 + j;
            C[(size_t)r * 512 + col] = f2bf(acc[j] + bv);
        }
    }
}

// ---------------------------------------------------------------------------
// Gather-aggregate (bf16 PQ): Hag[n] = sum relu(P[src]+Q[n]). Both graphs.
// ---------------------------------------------------------------------------
__global__ __launch_bounds__(256) void k_aggr(const short* __restrict__ PQ1,
                                              const short* __restrict__ PQ2,
                                              const int* __restrict__ coffs1,
                                              const int* __restrict__ srcb1,
                                              const int* __restrict__ coffs2,
                                              const int* __restrict__ srcb2,
                                              short* __restrict__ Hag1,
                                              short* __restrict__ Hag2, int N) {
    int gw = (blockIdx.x * 256 + threadIdx.x) >> 6;
    int lane = threadIdx.x & 63;
    const short* PQ; const int* offs; const int* srcb; short* Hag;
    if (gw < N) { PQ = PQ1; offs = coffs1; srcb = srcb1; Hag = Hag1; }
    else { gw -= N; if (gw >= N) return; PQ = PQ2; offs = coffs2; srcb = srcb2; Hag = Hag2; }
    short4b q4 = *(const short4b*)(PQ + (size_t)gw * 512 + 256 + lane * 4);
    float qx = bf2f(q4.x), qy = bf2f(q4.y), qz = bf2f(q4.z), qw = bf2f(q4.w);
    int e0 = offs[gw], e1 = offs[gw + 1];
    float ax = 0.f, ay = 0.f, az = 0.f, aw = 0.f;
    int e = e0;
    for (; e + 1 < e1; e += 2) {
        int s0 = srcb[e], s1 = srcb[e + 1];
        short4b pa = *(const short4b*)(PQ + (size_t)s0 * 512 + lane * 4);
        short4b pb = *(const short4b*)(PQ + (size_t)s1 * 512 + lane * 4);
        ax += fmaxf(bf2f(pa.x) + qx, 0.f) + fmaxf(bf2f(pb.x) + qx, 0.f);
        ay += fmaxf(bf2f(pa.y) + qy, 0.f) + fmaxf(bf2f(pb.y) + qy, 0.f);
        az += fmaxf(bf2f(pa.z) + qz, 0.f) + fmaxf(bf2f(pb.z) + qz, 0.f);
        aw += fmaxf(bf2f(pa.w) + qw, 0.f) + fmaxf(bf2f(pb.w) + qw, 0.f);
    }
    if (e < e1) {
        int s0 = srcb[e];
        short4b pa = *(const short4b*)(PQ + (size_t)s0 * 512 + lane * 4);
        ax += fmaxf(bf2f(pa.x) + qx, 0.f);
        ay += fmaxf(bf2f(pa.y) + qy, 0.f);
        az += fmaxf(bf2f(pa.z) + qz, 0.f);
        aw += fmaxf(bf2f(pa.w) + qw, 0.f);
    }
    short4b o;
    o.x = f2bf(ax); o.y = f2bf(ay); o.z = f2bf(az); o.w = f2bf(aw);
    *(short4b*)(Hag + (size_t)gw * HDIM + lane * 4) = o;
}

// ---------------------------------------------------------------------------
// MFMA GEMM: msg = Hag_bf @ msg_W2 + deg*b2 -> bf16 into U cols 0..255.
// ---------------------------------------------------------------------------
__global__ __launch_bounds__(256) void k_msg_mfma(const short* __restrict__ Hag1,
                                                  const short* __restrict__ Hag2,
                                                  const short* __restrict__ WmsgT,
                                                  const float* __restrict__ b2,
                                                  const int* __restrict__ deg1,
                                                  const int* __restrict__ deg2,
                                                  short* __restrict__ U1,
                                                  short* __restrict__ U2, int nblk) {
    int blk = blockIdx.x;
    const short* A; short* U; const int* deg;
    if (blk < nblk) { A = Hag1; U = U1; deg = deg1; }
    else { A = Hag2; U = U2; deg = deg2; blk -= nblk; }
    int w = threadIdx.x >> 6, l = threadIdx.x & 63;
    int row0 = blk * 32 + (w & 1) * 16;
    int ct0 = (w >> 1) * 8;
    int lm = l & 15, kg = (l >> 4) * 8;
    const short* Ar = A + (size_t)(row0 + lm) * 256 + kg;
    short8b a[8];
    #pragma unroll
    for (int ks = 0; ks < 8; ++ks) a[ks] = *(const short8b*)(Ar + ks * 32);
    float dg[4];
    #pragma unroll
    for (int j = 0; j < 4; ++j) dg[j] = (float)deg[row0 + (l >> 4) * 4 + j];
    for (int ct = ct0; ct < ct0 + 8; ++ct) {
        f32x4 acc = {0.f, 0.f, 0.f, 0.f};
        const short* Br = WmsgT + (size_t)(ct * 16 + lm) * 256 + kg;
        #pragma unroll
        for (int ks = 0; ks < 8; ++ks) {
            short8b b = *(const short8b*)(Br + ks * 32);
            acc = __builtin_amdgcn_mfma_f32_16x16x32_bf16(a[ks], b, acc, 0, 0, 0);
        }
        int col = ct * 16 + lm;
        float bv = b2[col];
        #pragma unroll
        for (int j = 0; j < 4; ++j) {
            int r = row0 + (l >> 4) * 4 + j;
            U[(size_t)r * 512 + col] = f2bf(acc[j] + dg[j] * bv);
        }
    }
}

// ---------------------------------------------------------------------------
// Attention tile core. Lane owns keys u*64+lane; q and p broadcast via
// v_readlane (VALU) instead of LDS. Ks rows beyond kt are zero-staged.
// ---------------------------------------------------------------------------
template<int NG>
__device__ __forceinline__ void attn_tile(const float (*Ks)[130],
                                          const float (&qreg)[4][2],
                                          float (&m)[4], float (&l)[4],
                                          float2 (&o)[4], float (&p)[3][4],
                                          int lane, int kt)
{
    float s[NG][4];
    #pragma unroll
    for (int u = 0; u < NG; ++u)
        #pragma unroll
        for (int r = 0; r < 4; ++r) s[u][r] = 0.f;
    int sw = swz(lane);
    #pragma unroll
    for (int h = 0; h < 2; ++h) {
        #pragma unroll 4
        for (int d4 = 0; d4 < 16; ++d4) {
            float4 kv[NG];
            #pragma unroll
            for (int u = 0; u < NG; ++u)
                kv[u] = *(const float4*)&Ks[u * 64 + lane][(h * 64 + d4 * 4) ^ sw];
            #pragma unroll
            for (int dd = 0; dd < 4; ++dd) {
                int dl = d4 * 4 + dd;
                #pragma unroll
                for (int r = 0; r < 4; ++r) {
                    float qv = rdlane(qreg[r][h], dl);
                    #pragma unroll
                    for (int u = 0; u < NG; ++u)
                        s[u][r] = fmaf(qv, kv[u][dd], s[u][r]);
                }
            }
        }
    }
    // online softmax update (row state in registers)
    #pragma unroll
    for (int r = 0; r < 4; ++r) {
        float mx = -1e30f;
        #pragma unroll
        for (int u = 0; u < NG; ++u) {
            float sv = (u * 64 + lane < kt) ? s[u][r] : -1e30f;
            s[u][r] = sv;
            mx = fmaxf(mx, sv);
        }
        #pragma unroll
        for (int off = 32; off; off >>= 1) mx = fmaxf(mx, __shfl_xor(mx, off));
        float nm = fmaxf(m[r], mx);
        float sc = __expf(m[r] - nm);
        float ps = 0.f;
        #pragma unroll
        for (int u = 0; u < NG; ++u) { float pv = __expf(s[u][r] - nm); p[u][r] = pv; ps += pv; }
        #pragma unroll
        for (int off = 32; off; off >>= 1) ps += __shfl_xor(ps, off);
        l[r] = l[r] * sc + ps;
        o[r].x *= sc; o[r].y *= sc;
        m[r] = nm;
    }
    // PV: lane owns dims (2*lane, 2*lane+1); p broadcast via readlane
    #pragma unroll
    for (int u = 0; u < NG; ++u) {
        #pragma unroll 8
        for (int cc = 0; cc < 64; ++cc) {
            float2 kv = *(const float2*)&Ks[u * 64 + cc][(2 * lane) ^ swz(cc)];
            #pragma unroll
            for (int r = 0; r < 4; ++r) {
                float pv = rdlane(p[u][r], cc);
                o[r].x = fmaf(pv, kv.x, o[r].x);
                o[r].y = fmaf(pv, kv.y, o[r].y);
            }
        }
    }
}

// ---------------------------------------------------------------------------
// Block-diagonal attention, both graphs in one launch.
// grid (64 batches, 2 row-halves, 2 directions); 512 threads, K resident
// in LDS (192 rows; tiled fallback for larger spans).
// Writes attn (bf16) into U cols 256..383.
// ---------------------------------------------------------------------------
__global__ __launch_bounds__(512) void k_attn(const float* __restrict__ x1,
                                              const float* __restrict__ x2,
                                              const int* __restrict__ offs1,
                                              const int* __restrict__ offs2,
                                              short* __restrict__ U1,
                                              short* __restrict__ U2)
{
    __shared__ float Ks[KSROWS][130];
    int b = blockIdx.x;
    int g = blockIdx.z;
    const float* xq = g ? x2 : x1;
    const float* xk = g ? x1 : x2;
    const int* offsq = g ? offs2 : offs1;
    const int* offsk = g ? offs1 : offs2;
    short* U = g ? U2 : U1;
    int q0 = offsq[b], q1 = offsq[b + 1];
    int k0 = offsk[b], k1 = offsk[b + 1];
    int nk = k1 - k0;
    int w = threadIdx.x >> 6, lane = threadIdx.x & 63;
    int tid = threadIdx.x;
    if (nk <= 0) return;

    if (nk <= KSROWS) {
        // fast path: whole K-span resident, staged once
        int ng = (nk + 63) >> 6;
        int tot = ng * 64 * 64;
        for (int idx = tid; idx < tot; idx += 512) {
            int row = idx >> 6, c2 = (idx & 63) * 2;
            float2 v = make_float2(0.f, 0.f);
            if (row < nk) v = *(const float2*)&xk[(size_t)(k0 + row) * DFEAT + c2];
            *(float2*)&Ks[row][c2 ^ swz(row)] = v;
        }
        __syncthreads();
        for (int qs0 = q0 + blockIdx.y * 32; qs0 < q1; qs0 += 64) {
            float qreg[4][2];
            #pragma unroll
            for (int r = 0; r < 4; ++r) {
                int row = qs0 + w * 4 + r;
                if (row < q1) {
                    qreg[r][0] = xq[(size_t)row * DFEAT + lane];
                    qreg[r][1] = xq[(size_t)row * DFEAT + 64 + lane];
                } else { qreg[r][0] = 0.f; qreg[r][1] = 0.f; }
            }
            float m[4], l[4]; float2 o[4]; float p[3][4];
            #pragma unroll
            for (int r = 0; r < 4; ++r) { m[r] = -1e30f; l[r] = 0.f; o[r] = make_float2(0.f, 0.f); }
            if (ng == 3)      attn_tile<3>(Ks, qreg, m, l, o, p, lane, nk);
            else if (ng == 2) attn_tile<2>(Ks, qreg, m, l, o, p, lane, nk);
            else              attn_tile<1>(Ks, qreg, m, l, o, p, lane, nk);
            #pragma unroll
            for (int r = 0; r < 4; ++r) {
                int row = qs0 + w * 4 + r;
                if (row < q1) {
                    float inv = 1.0f / l[r];
                    float2 xv = *(const float2*)&xq[(size_t)row * DFEAT + 2 * lane];
                    unsigned lo = (unsigned short)f2bf(xv.x - o[r].x * inv);
                    unsigned hi = (unsigned short)f2bf(xv.y - o[r].y * inv);
                    ((unsigned*)(U + (size_t)row * 512 + 256))[lane] = lo | (hi << 16);
                }
            }
        }
    } else {
        // general tiled path (rare: nk > 192)
        for (int qs0 = q0 + blockIdx.y * 32; qs0 < q1; qs0 += 64) {
            float qreg[4][2];
            #pragma unroll
            for (int r = 0; r < 4; ++r) {
                int row = qs0 + w * 4 + r;
                if (row < q1) {
                    qreg[r][0] = xq[(size_t)row * DFEAT + lane];
                    qreg[r][1] = xq[(size_t)row * DFEAT + 64 + lane];
                } else { qreg[r][0] = 0.f; qreg[r][1] = 0.f; }
            }
            float m[4], l[4]; float2 o[4]; float p[3][4];
            #pragma unroll
            for (int r = 0; r < 4; ++r) { m[r] = -1e30f; l[r] = 0.f; o[r] = make_float2(0.f, 0.f); }
            for (int t0 = 0; t0 < nk; t0 += KSROWS) {
                int kt = min(KSROWS, nk - t0);
                int ng = (kt + 63) >> 6;
                int tot = ng * 64 * 64;
                __syncthreads();
                for (int idx = tid; idx < tot; idx += 512) {
                    int row = idx >> 6, c2 = (idx & 63) * 2;
                    float2 v = make_float2(0.f, 0.f);
                    if (row < kt) v = *(const float2*)&xk[(size_t)(k0 + t0 + row) * DFEAT + c2];
                    *(float2*)&Ks[row][c2 ^ swz(row)] = v;
                }
                __syncthreads();
                if (ng == 3)      attn_tile<3>(Ks, qreg, m, l, o, p, lane, kt);
                else if (ng == 2) attn_tile<2>(Ks, qreg, m, l, o, p, lane, kt);
                else              attn_tile<1>(Ks, qreg, m, l, o, p, lane, kt);
            }
            #pragma unroll
            for (int r = 0; r < 4; ++r) {
                int row = qs0 + w * 4 + r;
                if (row < q1) {
                    float inv = 1.0f / l[r];
                    float2 xv = *(const float2*)&xq[(size_t)row * DFEAT + 2 * lane];
                    unsigned lo = (unsigned short)f2bf(xv.x - o[r].x * inv);
                    unsigned hi = (unsigned short)f2bf(xv.y - o[r].y * inv);
                    ((unsigned*)(U + (size_t)row * 512 + 256))[lane] = lo | (hi << 16);
                }
            }
        }
    }
}

// ---------------------------------------------------------------------------
// MFMA fused update: out = x + relu(U@Wu1 + b1) @ Wu2 + b2.
// ---------------------------------------------------------------------------
__global__ __launch_bounds__(256) void k_upd_mfma(const short* __restrict__ U1,
                                                  const short* __restrict__ U2,
                                                  const float* __restrict__ x1,
                                                  const float* __restrict__ x2,
                                                  const short* __restrict__ Wu1T,
                                                  const short* __restrict__ Wu2T,
                                                  const float* __restrict__ b1,
                                                  const float* __restrict__ b2,
                                                  float* __restrict__ out1,
                                                  float* __restrict__ out2, int nblk) {
    __shared__ short Hs[32][264];
    int blk = blockIdx.x;
    const short* Up; const float* x; float* out;
    if (blk < nblk) { Up = U1; x = x1; out = out1; }
    else { Up = U2; x = x2; out = out2; blk -= nblk; }
    int w = threadIdx.x >> 6, l = threadIdx.x & 63;
    int rw = (w & 1) * 16;
    int row0 = blk * 32 + rw;
    int lm = l & 15, kg = (l >> 4) * 8;

    int ct0 = (w >> 1) * 8;
    const short* Ar = Up + (size_t)(row0 + lm) * 512 + kg;
    short8b a[16];
    #pragma unroll
    for (int ks = 0; ks < 16; ++ks) a[ks] = *(const short8b*)(Ar + ks * 32);
    for (int ct = ct0; ct < ct0 + 8; ++ct) {
        f32x4 acc = {0.f, 0.f, 0.f, 0.f};
        const short* Br = Wu1T + (size_t)(ct * 16 + lm) * 512 + kg;
        #pragma unroll
        for (int ks = 0; ks < 16; ++ks) {
            short8b b = *(const short8b*)(Br + ks * 32);
            acc = __builtin_amdgcn_mfma_f32_16x16x32_bf16(a[ks], b, acc, 0, 0, 0);
        }
        int col = ct * 16 + lm;
        float bv = b1[col];
        #pragma unroll
        for (int j = 0; j < 4; ++j) {
            int r = rw + (l >> 4) * 4 + j;
            Hs[r][col] = f2bf(fmaxf(acc[j] + bv, 0.f));
        }
    }
    __syncthreads();

    int ct20 = (w >> 1) * 4;
    short8b a2[8];
    #pragma unroll
    for (int ks = 0; ks < 8; ++ks)
        a2[ks] = *(const short8b*)&Hs[rw + lm][ks * 32 + kg];
    for (int ct = ct20; ct < ct20 + 4; ++ct) {
        f32x4 acc = {0.f, 0.f, 0.f, 0.f};
        const short* Br = Wu2T + (size_t)(ct * 16 + lm) * 256 + kg;
        #pragma unroll
        for (int ks = 0; ks < 8; ++ks) {
            short8b b = *(const short8b*)(Br + ks * 32);
            acc = __builtin_amdgcn_mfma_f32_16x16x32_bf16(a2[ks], b, acc, 0, 0, 0);
        }
        int col = ct * 16 + lm;
        float bv = b2[col];
        #pragma unroll
        for (int j = 0; j < 4; ++j) {
            int r = row0 + (l >> 4) * 4 + j;
            out[(size_t)r * DFEAT + col] = x[(size_t)r * DFEAT + col] + acc[j] + bv;
        }
    }
}

// ---------------------------------------------------------------------------
extern "C" void kernel_launch(void* const* d_in, const int* in_sizes, int n_in,
                              void* d_out, int out_size, void* d_ws, size_t ws_size,
                              hipStream_t stream) {
    const float* x1     = (const float*)d_in[0];
    const int*   ei1    = (const int*)d_in[1];
    const int*   batch1 = (const int*)d_in[2];
    const float* x2     = (const float*)d_in[3];
    const int*   ei2    = (const int*)d_in[4];
    const int*   batch2 = (const int*)d_in[5];
    const float* msg_W1 = (const float*)d_in[6];
    const float* msg_b1 = (const float*)d_in[7];
    const float* msg_W2 = (const float*)d_in[8];
    const float* msg_b2 = (const float*)d_in[9];
    const float* upd_W1 = (const float*)d_in[10];
    const float* upd_b1 = (const float*)d_in[11];
    const float* upd_W2 = (const float*)d_in[12];
    const float* upd_b2 = (const float*)d_in[13];

    const int N = in_sizes[0] / DFEAT;   // 8192
    const int E = in_sizes[1] / 2;       // 131072

    char* base = (char*)d_ws;
    int* offs1   = (int*)base;                 // 128
    int* offs2   = offs1 + 128;                // 128
    int* deg1    = offs2 + 128;                // N
    int* deg2    = deg1 + N;                   // N
    int* coffs1  = deg2 + N;                   // N+64
    int* coffs2  = coffs1 + (N + 64);          // N+64
    int* cur1    = coffs2 + (N + 64);          // N
    int* cur2    = cur1 + N;                   // N
    int* srcb1   = cur2 + N;                   // E
    int* srcb2   = srcb1 + E;                  // E
    float* bias_pq = (float*)(srcb2 + E);      // 512
    short* S = (short*)(bias_pq + 512);
    size_t N512 = (size_t)N * 512;
    short* PQ1   = S;                          // N*512 bf16
    short* PQ2   = PQ1 + N512;
    short* Hag1  = PQ2 + N512;                 // N*256
    short* Hag2  = Hag1 + (size_t)N * 256;
    short* U1    = Hag2 + (size_t)N * 256;     // N*512
    short* U2    = U1 + N512;
    short* WpqT  = U2 + N512;                  // 512*128
    short* WmsgT = WpqT + 65536;               // 256*256
    short* Wu1T  = WmsgT + 65536;              // 256*512
    short* Wu2T  = Wu1T + 131072;              // 128*256

    hipMemsetAsync(deg1, 0, 2 * (size_t)N * sizeof(int), stream);

    int hb = (2 * E + 255) / 256;
    int xb = N / 4;
    int prep_blocks = 1 + hb + xb + 1154;
    k_prep<<<prep_blocks, 256, 0, stream>>>(batch1, batch2, ei1, ei2, x1, x2,
                                            msg_W1, msg_b1, msg_W2, upd_W1, upd_W2,
                                            N, E, offs1, offs2, deg1, deg2,
                                            U1, U2, WpqT, bias_pq, WmsgT, Wu1T, Wu2T);

    k_scan<<<2, 256, 0, stream>>>(deg1, deg2, N, coffs1, cur1, coffs2, cur2);
    k_scatter<<<(2 * E + 255) / 256, 256, 0, stream>>>(ei1, ei2, E, cur1, srcb1, cur2, srcb2);

    int nblk = N / 32;   // 256
    k_pq_mfma<<<2 * nblk, 256, 0, stream>>>(U1, U2, WpqT, bias_pq, PQ1, PQ2, nblk);

    k_aggr<<<2 * (N / 4), 256, 0, stream>>>(PQ1, PQ2, coffs1, srcb1, coffs2, srcb2,
                                            Hag1, Hag2, N);

    k_msg_mfma<<<2 * nblk, 256, 0, stream>>>(Hag1, Hag2, WmsgT, msg_b2,
                                             deg1, deg2, U1, U2, nblk);

    k_attn<<<dim3(64, 2, 2), 512, 0, stream>>>(x1, x2, offs1, offs2, U1, U2);

    float* out1 = (float*)d_out;
    float* out2 = out1 + (size_t)N * DFEAT;
    k_upd_mfma<<<2 * nblk, 256, 0, stream>>>(U1, U2, x1, x2, Wu1T, Wu2T,
                                             upd_b1, upd_b2, out1, out2, nblk);
}

// Round 9
// 277.828 us; speedup vs baseline: 1.2017x; 1.2017x over previous
//
#include <hip/hip_runtime.h>
#include <math.h>

#define DFEAT 128
#define HDIM 256
#define NT 10            // k-tiles per attention chunk
#define NCOLS 160        // NT*16
#define SVT 168          // V^T / P LDS stride in shorts: 336B = 21*16 -> 16B-aligned rows

typedef __attribute__((ext_vector_type(8))) short short8b;   // 8 bf16
typedef __attribute__((ext_vector_type(4))) short short4b;   // 4 bf16
typedef __attribute__((ext_vector_type(4))) float f32x4;

__device__ inline short f2bf(float f) {
    union { float f; unsigned u; } v; v.f = f;
    unsigned r = (v.u + 0x7fff + ((v.u >> 16) & 1)) >> 16;   // RNE
    return (short)r;
}
__device__ inline float bf2f(short s) {
    union { unsigned u; float f; } v; v.u = ((unsigned)(unsigned short)s) << 16;
    return v.f;
}

// ---------------------------------------------------------------------------
// k_prep: fused {batch offsets, degree histogram, weight cast, x cast->U+Xlo}.
// ---------------------------------------------------------------------------
__global__ __launch_bounds__(256) void k_prep(
    const int* __restrict__ batch1, const int* __restrict__ batch2,
    const int* __restrict__ ei1, const int* __restrict__ ei2,
    const float* __restrict__ x1, const float* __restrict__ x2,
    const float* __restrict__ msg_W1, const float* __restrict__ msg_b1,
    const float* __restrict__ msg_W2, const float* __restrict__ upd_W1,
    const float* __restrict__ upd_W2,
    int N, int E,
    int* __restrict__ offs1, int* __restrict__ offs2,
    int* __restrict__ deg1, int* __restrict__ deg2,
    short* __restrict__ U1, short* __restrict__ U2,
    short* __restrict__ Xlo1, short* __restrict__ Xlo2,
    short* __restrict__ WpqT, float* __restrict__ bias_pq,
    short* __restrict__ WmsgT, short* __restrict__ Wu1T, short* __restrict__ Wu2T)
{
    int hb = (2 * E + 255) >> 8;
    int xb = N >> 2;
    int bid = blockIdx.x;
    if (bid == 0) {                  // batch segment offsets (binary search)
        int t = threadIdx.x;
        if (t < 130) {
            const int* batch = (t < 65) ? batch1 : batch2;
            int b = (t < 65) ? t : t - 65;
            int lo = 0, hi = N;
            while (lo < hi) { int mid = (lo + hi) >> 1; if (batch[mid] < b) lo = mid + 1; else hi = mid; }
            if (t < 65) offs1[b] = lo; else offs2[b] = lo;
        }
        return;
    }
    bid -= 1;
    if (bid < hb) {                  // degree histogram
        int t = bid * 256 + threadIdx.x;
        if (t < E) atomicAdd(deg1 + ei1[t], 1);
        else if (t < 2 * E) atomicAdd(deg2 + ei2[t - E], 1);
        return;
    }
    bid -= hb;
    if (bid < xb) {                  // x -> bf16 hi into U cols 384.., lo -> Xlo
        int t = bid * 256 + threadIdx.x;
        int per = N * 32;
        const float* x; short* U; short* XL;
        if (t < per) { x = x1; U = U1; XL = Xlo1; } else { x = x2; U = U2; XL = Xlo2; t -= per; }
        int row = t >> 5, i4 = (t & 31) * 4;
        float4 v = *(const float4*)&x[(size_t)row * DFEAT + i4];
        short4b s; s.x = f2bf(v.x); s.y = f2bf(v.y); s.z = f2bf(v.z); s.w = f2bf(v.w);
        *(short4b*)&U[(size_t)row * 512 + 384 + i4] = s;
        short4b lo;
        lo.x = f2bf(v.x - bf2f(s.x));
        lo.y = f2bf(v.y - bf2f(s.y));
        lo.z = f2bf(v.z - bf2f(s.z));
        lo.w = f2bf(v.w - bf2f(s.w));
        *(short4b*)&XL[(size_t)row * DFEAT + i4] = lo;
        return;
    }
    bid -= xb;
    {                                // weight casts
        int t = bid * 256 + threadIdx.x;
        if (t < 65536) {             // WpqT[512][128]
            int j = t >> 7, k = t & 127;
            float v = (j < 256) ? msg_W1[(size_t)k * 256 + j]
                                : msg_W1[(size_t)(128 + k) * 256 + (j - 256)];
            WpqT[t] = f2bf(v);
            return;
        }
        t -= 65536;
        if (t < 512) { bias_pq[t] = (t < 256) ? msg_b1[t] : 0.f; return; }
        t -= 512;
        if (t < 65536) {             // WmsgT[256][256]
            int j = t >> 8, k = t & 255;
            WmsgT[t] = f2bf(msg_W2[(size_t)k * 256 + j]);
            return;
        }
        t -= 65536;
        if (t < 131072) {            // Wu1T[256][512]
            int j = t >> 9, k = t & 511;
            Wu1T[t] = f2bf(upd_W1[(size_t)k * 256 + j]);
            return;
        }
        t -= 131072;
        if (t < 32768) {             // Wu2T[128][256]
            int j = t >> 8, k = t & 255;
            Wu2T[t] = f2bf(upd_W2[(size_t)k * 128 + j]);
        }
    }
}

// ---------------------------------------------------------------------------
// CSR build: scan + scatter.
// ---------------------------------------------------------------------------
__global__ __launch_bounds__(256) void k_scan(const int* __restrict__ deg1,
                                              const int* __restrict__ deg2, int N,
                                              int* __restrict__ offs1, int* __restrict__ cur1,
                                              int* __restrict__ offs2, int* __restrict__ cur2) {
    const int* deg = blockIdx.x ? deg2 : deg1;
    int* offs = blockIdx.x ? offs2 : offs1;
    int* cur  = blockIdx.x ? cur2  : cur1;
    int t = threadIdx.x;
    int base = t * 32;
    int vals[32];
    int run = 0;
    #pragma unroll
    for (int i = 0; i < 32; ++i) { vals[i] = run; run += deg[base + i]; }
    __shared__ int tot[256];
    tot[t] = run;
    __syncthreads();
    for (int off = 1; off < 256; off <<= 1) {
        int v = (t >= off) ? tot[t - off] : 0;
        __syncthreads();
        tot[t] += v;
        __syncthreads();
    }
    int prefix = (t == 0) ? 0 : tot[t - 1];
    #pragma unroll
    for (int i = 0; i < 32; ++i) {
        int o = prefix + vals[i];
        offs[base + i] = o;
        cur[base + i] = o;
    }
    if (t == 255) offs[N] = tot[255];
}

__global__ __launch_bounds__(256) void k_scatter(const int* __restrict__ ei1,
                                                 const int* __restrict__ ei2, int E,
                                                 int* __restrict__ cur1, int* __restrict__ srcb1,
                                                 int* __restrict__ cur2, int* __restrict__ srcb2) {
    int t = blockIdx.x * 256 + threadIdx.x;
    if (t < E) {
        int tgt = ei1[t], src = ei1[E + t];
        srcb1[atomicAdd(cur1 + tgt, 1)] = src;
    } else if (t < 2 * E) {
        int e = t - E;
        int tgt = ei2[e], src = ei2[E + e];
        srcb2[atomicAdd(cur2 + tgt, 1)] = src;
    }
}

// ---------------------------------------------------------------------------
// MFMA GEMM: PQ_bf16[N][512] = x_bf(U cols 384..511) @ Wpq + bias.
// ---------------------------------------------------------------------------
__global__ __launch_bounds__(256) void k_pq_mfma(const short* __restrict__ U1,
                                                 const short* __restrict__ U2,
                                                 const short* __restrict__ WpqT,
                                                 const float* __restrict__ bias,
                                                 short* __restrict__ PQ1,
                                                 short* __restrict__ PQ2, int nblk) {
    int blk = blockIdx.x;
    const short* A; short* C;
    if (blk < nblk) { A = U1; C = PQ1; } else { A = U2; C = PQ2; blk -= nblk; }
    int w = threadIdx.x >> 6, l = threadIdx.x & 63;
    int row0 = blk * 32 + (w & 1) * 16;
    int ct0 = (w >> 1) * 16;
    int lm = l & 15, kg = (l >> 4) * 8;
    const short* Ar = A + (size_t)(row0 + lm) * 512 + 384 + kg;
    short8b a[4];
    #pragma unroll
    for (int ks = 0; ks < 4; ++ks) a[ks] = *(const short8b*)(Ar + ks * 32);
    for (int ct = ct0; ct < ct0 + 16; ++ct) {
        f32x4 acc = {0.f, 0.f, 0.f, 0.f};
        const short* Br = WpqT + (size_t)(ct * 16 + lm) * 128 + kg;
        #pragma unroll
        for (int ks = 0; ks < 4; ++ks) {
            short8b b = *(const short8b*)(Br + ks * 32);
            acc = __builtin_amdgcn_mfma_f32_16x16x32_bf16(a[ks], b, acc, 0, 0, 0);
        }
        int col = ct * 16 + lm;
        float bv = bias[col];
        #pragma unroll
        for (int j = 0; j < 4; ++j) {
            int r = row0 + (l >> 4) * 4 + j;
            C[(size_t)r * 512 + col] = f2bf(acc[j] + bv);
        }
    }
}

// ---------------------------------------------------------------------------
// Gather-aggregate (bf16 PQ): Hag[n] = sum relu(P[src]+Q[n]). Both graphs.
// ---------------------------------------------------------------------------
__global__ __launch_bounds__(256) void k_aggr(const short* __restrict__ PQ1,
                                              const short* __restrict__ PQ2,
                                              const int* __restrict__ coffs1,
                                              const int* __restrict__ srcb1,
                                              const int* __restrict__ coffs2,
                                              const int* __restrict__ srcb2,
                                              short* __restrict__ Hag1,
                                              short* __restrict__ Hag2, int N) {
    int gw = (blockIdx.x * 256 + threadIdx.x) >> 6;
    int lane = threadIdx.x & 63;
    const short* PQ; const int* offs; const int* srcb; short* Hag;
    if (gw < N) { PQ = PQ1; offs = coffs1; srcb = srcb1; Hag = Hag1; }
    else { gw -= N; if (gw >= N) return; PQ = PQ2; offs = coffs2; srcb = srcb2; Hag = Hag2; }
    short4b q4 = *(const short4b*)(PQ + (size_t)gw * 512 + 256 + lane * 4);
    float qx = bf2f(q4.x), qy = bf2f(q4.y), qz = bf2f(q4.z), qw = bf2f(q4.w);
    int e0 = offs[gw], e1 = offs[gw + 1];
    float ax = 0.f, ay = 0.f, az = 0.f, aw = 0.f;
    int e = e0;
    for (; e + 1 < e1; e += 2) {
        int s0 = srcb[e], s1 = srcb[e + 1];
        short4b pa = *(const short4b*)(PQ + (size_t)s0 * 512 + lane * 4);
        short4b pb = *(const short4b*)(PQ + (size_t)s1 * 512 + lane * 4);
        ax += fmaxf(bf2f(pa.x) + qx, 0.f) + fmaxf(bf2f(pb.x) + qx, 0.f);
        ay += fmaxf(bf2f(pa.y) + qy, 0.f) + fmaxf(bf2f(pb.y) + qy, 0.f);
        az += fmaxf(bf2f(pa.z) + qz, 0.f) + fmaxf(bf2f(pb.z) + qz, 0.f);
        aw += fmaxf(bf2f(pa.w) + qw, 0.f) + fmaxf(bf2f(pb.w) + qw, 0.f);
    }
    if (e < e1) {
        int s0 = srcb[e];
        short4b pa = *(const short4b*)(PQ + (size_t)s0 * 512 + lane * 4);
        ax += fmaxf(bf2f(pa.x) + qx, 0.f);
        ay += fmaxf(bf2f(pa.y) + qy, 0.f);
        az += fmaxf(bf2f(pa.z) + qz, 0.f);
        aw += fmaxf(bf2f(pa.w) + qw, 0.f);
    }
    short4b o;
    o.x = f2bf(ax); o.y = f2bf(ay); o.z = f2bf(az); o.w = f2bf(aw);
    *(short4b*)(Hag + (size_t)gw * HDIM + lane * 4) = o;
}

// ---------------------------------------------------------------------------
// MFMA GEMM: msg = Hag_bf @ msg_W2 + deg*b2 -> bf16 into U cols 0..255.
// ---------------------------------------------------------------------------
__global__ __launch_bounds__(256) void k_msg_mfma(const short* __restrict__ Hag1,
                                                  const short* __restrict__ Hag2,
                                                  const short* __restrict__ WmsgT,
                                                  const float* __restrict__ b2,
                                                  const int* __restrict__ deg1,
                                                  const int* __restrict__ deg2,
                                                  short* __restrict__ U1,
                                                  short* __restrict__ U2, int nblk) {
    int blk = blockIdx.x;
    const short* A; short* U; const int* deg;
    if (blk < nblk) { A = Hag1; U = U1; deg = deg1; }
    else { A = Hag2; U = U2; deg = deg2; blk -= nblk; }
    int w = threadIdx.x >> 6, l = threadIdx.x & 63;
    int row0 = blk * 32 + (w & 1) * 16;
    int ct0 = (w >> 1) * 8;
    int lm = l & 15, kg = (l >> 4) * 8;
    const short* Ar = A + (size_t)(row0 + lm) * 256 + kg;
    short8b a[8];
    #pragma unroll
    for (int ks = 0; ks < 8; ++ks) a[ks] = *(const short8b*)(Ar + ks * 32);
    float dg[4];
    #pragma unroll
    for (int j = 0; j < 4; ++j) dg[j] = (float)deg[row0 + (l >> 4) * 4 + j];
    for (int ct = ct0; ct < ct0 + 8; ++ct) {
        f32x4 acc = {0.f, 0.f, 0.f, 0.f};
        const short* Br = WmsgT + (size_t)(ct * 16 + lm) * 256 + kg;
        #pragma unroll
        for (int ks = 0; ks < 8; ++ks) {
            short8b b = *(const short8b*)(Br + ks * 32);
            acc = __builtin_amdgcn_mfma_f32_16x16x32_bf16(a[ks], b, acc, 0, 0, 0);
        }
        int col = ct * 16 + lm;
        float bv = b2[col];
        #pragma unroll
        for (int j = 0; j < 4; ++j) {
            int r = row0 + (l >> 4) * 4 + j;
            U[(size_t)r * 512 + col] = f2bf(acc[j] + dg[j] * bv);
        }
    }
}

// ---------------------------------------------------------------------------
// MFMA flash attention over block-diagonal mask (v3: K-frags from GLOBAL).
// grid (64 batches, 2 tile-groups, 2 directions); 256 threads / 4 waves.
// Split-bf16 QK^T (Qh*Kh + Ql*Kh + Qh*Kl) with B-fragments loaded directly
// from global (validated addressing pattern). LDS only for V^T and P,
// both fully zero-filled. Writes attn (bf16) into U cols 256..383.
// ---------------------------------------------------------------------------
__global__ __launch_bounds__(256) void k_attn(
    const float* __restrict__ x1, const float* __restrict__ x2,
    const short* __restrict__ Xlo1, const short* __restrict__ Xlo2,
    const int* __restrict__ offs1, const int* __restrict__ offs2,
    short* __restrict__ U1, short* __restrict__ U2)
{
    alignas(16) __shared__ short Vt[128][SVT];     // V^T (hi), [d][c]
    alignas(16) __shared__ short Pl[4][16][SVT];   // per-wave P, [qrow][c]
    int b = blockIdx.x, g = blockIdx.z;
    const float* xq   = g ? x2 : x1;
    const short* Uq   = g ? U2 : U1;
    const short* Loq  = g ? Xlo2 : Xlo1;
    const short* Uk   = g ? U1 : U2;
    const short* Lok  = g ? Xlo1 : Xlo2;
    const int* offsq  = g ? offs2 : offs1;
    const int* offsk  = g ? offs1 : offs2;
    short* Uo = g ? U2 : U1;
    int q0 = offsq[b], q1 = offsq[b + 1];
    int k0 = offsk[b], k1 = offsk[b + 1];
    int nk = k1 - k0;
    int nq = q1 - q0;
    if (nk <= 0 || nq <= 0) return;
    int w = threadIdx.x >> 6, l = threadIdx.x & 63;
    int lm = l & 15, gq = l >> 4;
    int tid = threadIdx.x;
    int nqt = (nq + 15) >> 4;
    int I = (nqt + 7) >> 3;

    for (int i = 0; i < I; ++i) {
        int tq = i * 8 + blockIdx.y * 4 + w;
        bool active = (tq < nqt);
        int r0 = q0 + tq * 16;
        // A-frags (Q hi/lo) straight from global, clamped rows
        short8b ah[4], al[4];
        if (active) {
            int arow = min(r0 + lm, q1 - 1);
            const short* Aq = Uq + (size_t)arow * 512 + 384 + gq * 8;
            const short* Alo = Loq + (size_t)arow * DFEAT + gq * 8;
            #pragma unroll
            for (int ks = 0; ks < 4; ++ks) {
                ah[ks] = *(const short8b*)(Aq + ks * 32);
                al[ks] = *(const short8b*)(Alo + ks * 32);
            }
        }
        float m[4], lsum[4];
        f32x4 O[8];
        #pragma unroll
        for (int j = 0; j < 4; ++j) { m[j] = -1e30f; lsum[j] = 0.f; }
        #pragma unroll
        for (int dt = 0; dt < 8; ++dt) O[dt] = (f32x4){0.f, 0.f, 0.f, 0.f};

        for (int t0 = 0; t0 < nk; t0 += NCOLS) {
            int ktlen = min(NCOLS, nk - t0);
            __syncthreads();   // previous chunk's PV fully consumed Vt
            // --- cooperative stage: V^T (transposed hi), zero-filled ---
            for (int idx = tid; idx < NCOLS * 16; idx += 256) {
                int row = idx >> 4, ch = idx & 15;
                if (row < ktlen) {
                    int grow = k0 + t0 + row;
                    short8b hi = *(const short8b*)(Uk + (size_t)grow * 512 + 384 + ch * 8);
                    #pragma unroll
                    for (int ii = 0; ii < 8; ++ii)
                        Vt[ch * 8 + ii][row] = hi[ii];
                } else {
                    #pragma unroll
                    for (int ii = 0; ii < 8; ++ii)
                        Vt[ch * 8 + ii][row] = 0;
                }
            }
            __syncthreads();
            if (!active) continue;

            // --- QK^T (split), K-fragments directly from global ---
            f32x4 s[NT];
            #pragma unroll
            for (int kt = 0; kt < NT; ++kt) s[kt] = (f32x4){0.f, 0.f, 0.f, 0.f};
            #pragma unroll
            for (int kt = 0; kt < NT; ++kt) {
                if (kt * 16 < ktlen) {
                    int krow = min(k0 + t0 + kt * 16 + lm, k1 - 1);
                    const short* Bh = Uk + (size_t)krow * 512 + 384 + gq * 8;
                    const short* Bl = Lok + (size_t)krow * DFEAT + gq * 8;
                    #pragma unroll
                    for (int ks = 0; ks < 4; ++ks) {
                        short8b bh = *(const short8b*)(Bh + ks * 32);
                        short8b bl = *(const short8b*)(Bl + ks * 32);
                        s[kt] = __builtin_amdgcn_mfma_f32_16x16x32_bf16(ah[ks], bh, s[kt], 0, 0, 0);
                        s[kt] = __builtin_amdgcn_mfma_f32_16x16x32_bf16(al[ks], bh, s[kt], 0, 0, 0);
                        s[kt] = __builtin_amdgcn_mfma_f32_16x16x32_bf16(ah[ks], bl, s[kt], 0, 0, 0);
                    }
                }
            }
            // --- masked online softmax (row=gq*4+j, col=kt*16+lm) ---
            float tm[4] = {-1e30f, -1e30f, -1e30f, -1e30f};
            #pragma unroll
            for (int kt = 0; kt < NT; ++kt) {
                bool v = (kt * 16 + lm) < ktlen;
                #pragma unroll
                for (int j = 0; j < 4; ++j) {
                    float sv = v ? s[kt][j] : -1e30f;
                    s[kt][j] = sv;
                    tm[j] = fmaxf(tm[j], sv);
                }
            }
            #pragma unroll
            for (int j = 0; j < 4; ++j) {
                #pragma unroll
                for (int off = 8; off; off >>= 1) tm[j] = fmaxf(tm[j], __shfl_xor(tm[j], off));
            }
            float sc[4], ps[4];
            #pragma unroll
            for (int j = 0; j < 4; ++j) {
                float nm = fmaxf(m[j], tm[j]);
                sc[j] = __expf(m[j] - nm);
                m[j] = nm;
                ps[j] = 0.f;
            }
            #pragma unroll
            for (int kt = 0; kt < NT; ++kt) {
                #pragma unroll
                for (int j = 0; j < 4; ++j) {
                    float pv = __expf(s[kt][j] - m[j]);
                    ps[j] += pv;
                    Pl[w][gq * 4 + j][kt * 16 + lm] = f2bf(pv);
                }
            }
            #pragma unroll
            for (int j = 0; j < 4; ++j) {
                #pragma unroll
                for (int off = 8; off; off >>= 1) ps[j] += __shfl_xor(ps[j], off);
                lsum[j] = lsum[j] * sc[j] + ps[j];
            }
            #pragma unroll
            for (int dt = 0; dt < 8; ++dt)
                #pragma unroll
                for (int j = 0; j < 4; ++j) O[dt][j] *= sc[j];

            // --- PV: O += P @ V  (A from Pl, B from Vt) ---
            int nks = (ktlen + 31) >> 5;
            for (int ks = 0; ks < nks; ++ks) {
                const short* ap = (const short*)Pl[w] + lm * SVT + ks * 32 + gq * 8;
                short8b a = *(const short8b*)ap;
                #pragma unroll
                for (int dt = 0; dt < 8; ++dt) {
                    const short* vb = (const short*)Vt + (dt * 16 + lm) * SVT + ks * 32 + gq * 8;
                    short8b bv = *(const short8b*)vb;
                    O[dt] = __builtin_amdgcn_mfma_f32_16x16x32_bf16(a, bv, O[dt], 0, 0, 0);
                }
            }
        }
        // --- write attn = x - O/l into U cols 256..383 ---
        if (active) {
            float inv[4];
            #pragma unroll
            for (int j = 0; j < 4; ++j) inv[j] = 1.0f / lsum[j];
            #pragma unroll
            for (int dt = 0; dt < 8; ++dt) {
                #pragma unroll
                for (int j = 0; j < 4; ++j) {
                    int qrow = r0 + gq * 4 + j;
                    if (qrow < q1) {
                        int d = dt * 16 + lm;
                        float xv = xq[(size_t)qrow * DFEAT + d];
                        Uo[(size_t)qrow * 512 + 256 + d] = f2bf(xv - O[dt][j] * inv[j]);
                    }
                }
            }
        }
    }
}

// ---------------------------------------------------------------------------
// MFMA fused update: out = x + relu(U@Wu1 + b1) @ Wu2 + b2.
// ---------------------------------------------------------------------------
__global__ __launch_bounds__(256) void k_upd_mfma(const short* __restrict__ U1,
                                                  const short* __restrict__ U2,
                                                  const float* __restrict__ x1,
                                                  const float* __restrict__ x2,
                                                  const short* __restrict__ Wu1T,
                                                  const short* __restrict__ Wu2T,
                                                  const float* __restrict__ b1,
                                                  const float* __restrict__ b2,
                                                  float* __restrict__ out1,
                                                  float* __restrict__ out2, int nblk) {
    __shared__ short Hs[32][264];
    int blk = blockIdx.x;
    const short* Up; const float* x; float* out;
    if (blk < nblk) { Up = U1; x = x1; out = out1; }
    else { Up = U2; x = x2; out = out2; blk -= nblk; }
    int w = threadIdx.x >> 6, l = threadIdx.x & 63;
    int rw = (w & 1) * 16;
    int row0 = blk * 32 + rw;
    int lm = l & 15, kg = (l >> 4) * 8;

    int ct0 = (w >> 1) * 8;
    const short* Ar = Up + (size_t)(row0 + lm) * 512 + kg;
    short8b a[16];
    #pragma unroll
    for (int ks = 0; ks < 16; ++ks) a[ks] = *(const short8b*)(Ar + ks * 32);
    for (int ct = ct0; ct < ct0 + 8; ++ct) {
        f32x4 acc = {0.f, 0.f, 0.f, 0.f};
        const short* Br = Wu1T + (size_t)(ct * 16 + lm) * 512 + kg;
        #pragma unroll
        for (int ks = 0; ks < 16; ++ks) {
            short8b b = *(const short8b*)(Br + ks * 32);
            acc = __builtin_amdgcn_mfma_f32_16x16x32_bf16(a[ks], b, acc, 0, 0, 0);
        }
        int col = ct * 16 + lm;
        float bv = b1[col];
        #pragma unroll
        for (int j = 0; j < 4; ++j) {
            int r = rw + (l >> 4) * 4 + j;
            Hs[r][col] = f2bf(fmaxf(acc[j] + bv, 0.f));
        }
    }
    __syncthreads();

    int ct20 = (w >> 1) * 4;
    short8b a2[8];
    #pragma unroll
    for (int ks = 0; ks < 8; ++ks)
        a2[ks] = *(const short8b*)&Hs[rw + lm][ks * 32 + kg];
    for (int ct = ct20; ct < ct20 + 4; ++ct) {
        f32x4 acc = {0.f, 0.f, 0.f, 0.f};
        const short* Br = Wu2T + (size_t)(ct * 16 + lm) * 256 + kg;
        #pragma unroll
        for (int ks = 0; ks < 8; ++ks) {
            short8b b = *(const short8b*)(Br + ks * 32);
            acc = __builtin_amdgcn_mfma_f32_16x16x32_bf16(a2[ks], b, acc, 0, 0, 0);
        }
        int col = ct * 16 + lm;
        float bv = b2[col];
        #pragma unroll
        for (int j = 0; j < 4; ++j) {
            int r = row0 + (l >> 4) * 4 + j;
            out[(size_t)r * DFEAT + col] = x[(size_t)r * DFEAT + col] + acc[j] + bv;
        }
    }
}

// ---------------------------------------------------------------------------
extern "C" void kernel_launch(void* const* d_in, const int* in_sizes, int n_in,
                              void* d_out, int out_size, void* d_ws, size_t ws_size,
                              hipStream_t stream) {
    const float* x1     = (const float*)d_in[0];
    const int*   ei1    = (const int*)d_in[1];
    const int*   batch1 = (const int*)d_in[2];
    const float* x2     = (const float*)d_in[3];
    const int*   ei2    = (const int*)d_in[4];
    const int*   batch2 = (const int*)d_in[5];
    const float* msg_W1 = (const float*)d_in[6];
    const float* msg_b1 = (const float*)d_in[7];
    const float* msg_W2 = (const float*)d_in[8];
    const float* msg_b2 = (const float*)d_in[9];
    const float* upd_W1 = (const float*)d_in[10];
    const float* upd_b1 = (const float*)d_in[11];
    const float* upd_W2 = (const float*)d_in[12];
    const float* upd_b2 = (const float*)d_in[13];

    const int N = in_sizes[0] / DFEAT;   // 8192
    const int E = in_sizes[1] / 2;       // 131072

    char* base = (char*)d_ws;
    int* offs1   = (int*)base;                 // 128
    int* offs2   = offs1 + 128;                // 128
    int* deg1    = offs2 + 128;                // N
    int* deg2    = deg1 + N;                   // N
    int* coffs1  = deg2 + N;                   // N+64
    int* coffs2  = coffs1 + (N + 64);          // N+64
    int* cur1    = coffs2 + (N + 64);          // N
    int* cur2    = cur1 + N;                   // N
    int* srcb1   = cur2 + N;                   // E
    int* srcb2   = srcb1 + E;                  // E
    float* bias_pq = (float*)(srcb2 + E);      // 512
    short* S = (short*)(bias_pq + 512);
    size_t N512 = (size_t)N * 512;
    short* PQ1   = S;                          // N*512 bf16
    short* PQ2   = PQ1 + N512;
    short* Hag1  = PQ2 + N512;                 // N*256
    short* Hag2  = Hag1 + (size_t)N * 256;
    short* U1    = Hag2 + (size_t)N * 256;     // N*512
    short* U2    = U1 + N512;
    short* Xlo1  = U2 + N512;                  // N*128
    short* Xlo2  = Xlo1 + (size_t)N * 128;
    short* WpqT  = Xlo2 + (size_t)N * 128;     // 512*128
    short* WmsgT = WpqT + 65536;               // 256*256
    short* Wu1T  = WmsgT + 65536;              // 256*512
    short* Wu2T  = Wu1T + 131072;              // 128*256

    hipMemsetAsync(deg1, 0, 2 * (size_t)N * sizeof(int), stream);

    int hb = (2 * E + 255) / 256;
    int xb = N / 4;
    int prep_blocks = 1 + hb + xb + 1154;
    k_prep<<<prep_blocks, 256, 0, stream>>>(batch1, batch2, ei1, ei2, x1, x2,
                                            msg_W1, msg_b1, msg_W2, upd_W1, upd_W2,
                                            N, E, offs1, offs2, deg1, deg2,
                                            U1, U2, Xlo1, Xlo2,
                                            WpqT, bias_pq, WmsgT, Wu1T, Wu2T);

    k_scan<<<2, 256, 0, stream>>>(deg1, deg2, N, coffs1, cur1, coffs2, cur2);
    k_scatter<<<(2 * E + 255) / 256, 256, 0, stream>>>(ei1, ei2, E, cur1, srcb1, cur2, srcb2);

    int nblk = N / 32;   // 256
    k_pq_mfma<<<2 * nblk, 256, 0, stream>>>(U1, U2, WpqT, bias_pq, PQ1, PQ2, nblk);

    k_aggr<<<2 * (N / 4), 256, 0, stream>>>(PQ1, PQ2, coffs1, srcb1, coffs2, srcb2,
                                            Hag1, Hag2, N);

    k_msg_mfma<<<2 * nblk, 256, 0, stream>>>(Hag1, Hag2, WmsgT, msg_b2,
                                             deg1, deg2, U1, U2, nblk);

    k_attn<<<dim3(64, 2, 2), 256, 0, stream>>>(x1, x2, Xlo1, Xlo2, offs1, offs2, U1, U2);

    float* out1 = (float*)d_out;
    float* out2 = out1 + (size_t)N * DFEAT;
    k_upd_mfma<<<2 * nblk, 256, 0, stream>>>(U1, U2, x1, x2, Wu1T, Wu2T,
                                             upd_b1, upd_b2, out1, out2, nblk);
}

// Round 10
// 271.113 us; speedup vs baseline: 1.2314x; 1.0248x over previous
//
#include <hip/hip_runtime.h>
#include <math.h>

#define DFEAT 128
#define HDIM 256
#define ANT 8            // k-tiles per attention chunk
#define ANC 128          // ANT*16 cols per chunk
#define SVP 136          // P LDS stride in shorts (272B = 17*16, 16B-aligned rows)

typedef __attribute__((ext_vector_type(8))) short short8b;   // 8 bf16
typedef __attribute__((ext_vector_type(4))) short short4b;   // 4 bf16
typedef __attribute__((ext_vector_type(4))) float f32x4;

__device__ inline short f2bf(float f) {
    union { float f; unsigned u; } v; v.f = f;
    unsigned r = (v.u + 0x7fff + ((v.u >> 16) & 1)) >> 16;   // RNE
    return (short)r;
}
__device__ inline float bf2f(short s) {
    union { unsigned u; float f; } v; v.u = ((unsigned)(unsigned short)s) << 16;
    return v.f;
}

// ---------------------------------------------------------------------------
// k_prep: fused {batch offsets + aligned key offsets, degree histogram,
// weight cast, x cast->U+Xlo}.
// ---------------------------------------------------------------------------
__global__ __launch_bounds__(256) void k_prep(
    const int* __restrict__ batch1, const int* __restrict__ batch2,
    const int* __restrict__ ei1, const int* __restrict__ ei2,
    const float* __restrict__ x1, const float* __restrict__ x2,
    const float* __restrict__ msg_W1, const float* __restrict__ msg_b1,
    const float* __restrict__ msg_W2, const float* __restrict__ upd_W1,
    const float* __restrict__ upd_W2,
    int N, int E,
    int* __restrict__ offs1, int* __restrict__ offs2,
    int* __restrict__ aoff1, int* __restrict__ aoff2,
    int* __restrict__ deg1, int* __restrict__ deg2,
    short* __restrict__ U1, short* __restrict__ U2,
    short* __restrict__ Xlo1, short* __restrict__ Xlo2,
    short* __restrict__ WpqT, float* __restrict__ bias_pq,
    short* __restrict__ WmsgT, short* __restrict__ Wu1T, short* __restrict__ Wu2T)
{
    int hb = (2 * E + 255) >> 8;
    int xb = N >> 2;
    int bid = blockIdx.x;
    if (bid == 0) {                  // batch segment offsets + aligned offsets
        int t = threadIdx.x;
        if (t < 130) {
            const int* batch = (t < 65) ? batch1 : batch2;
            int b = (t < 65) ? t : t - 65;
            int lo = 0, hi = N;
            while (lo < hi) { int mid = (lo + hi) >> 1; if (batch[mid] < b) lo = mid + 1; else hi = mid; }
            if (t < 65) offs1[b] = lo; else offs2[b] = lo;
        }
        __syncthreads();
        if (t < 2) {
            const int* offs = t ? offs2 : offs1;
            int* aoff = t ? aoff2 : aoff1;
            int acc = 0;
            for (int bb = 0; bb < 64; ++bb) {
                aoff[bb] = acc;
                acc += (offs[bb + 1] - offs[bb] + 7) & ~7;
            }
            aoff[64] = acc;
        }
        return;
    }
    bid -= 1;
    if (bid < hb) {                  // degree histogram
        int t = bid * 256 + threadIdx.x;
        if (t < E) atomicAdd(deg1 + ei1[t], 1);
        else if (t < 2 * E) atomicAdd(deg2 + ei2[t - E], 1);
        return;
    }
    bid -= hb;
    if (bid < xb) {                  // x -> bf16 hi into U cols 384.., lo -> Xlo
        int t = bid * 256 + threadIdx.x;
        int per = N * 32;
        const float* x; short* U; short* XL;
        if (t < per) { x = x1; U = U1; XL = Xlo1; } else { x = x2; U = U2; XL = Xlo2; t -= per; }
        int row = t >> 5, i4 = (t & 31) * 4;
        float4 v = *(const float4*)&x[(size_t)row * DFEAT + i4];
        short4b s; s.x = f2bf(v.x); s.y = f2bf(v.y); s.z = f2bf(v.z); s.w = f2bf(v.w);
        *(short4b*)&U[(size_t)row * 512 + 384 + i4] = s;
        short4b lo;
        lo.x = f2bf(v.x - bf2f(s.x));
        lo.y = f2bf(v.y - bf2f(s.y));
        lo.z = f2bf(v.z - bf2f(s.z));
        lo.w = f2bf(v.w - bf2f(s.w));
        *(short4b*)&XL[(size_t)row * DFEAT + i4] = lo;
        return;
    }
    bid -= xb;
    {                                // weight casts
        int t = bid * 256 + threadIdx.x;
        if (t < 65536) {             // WpqT[512][128]
            int j = t >> 7, k = t & 127;
            float v = (j < 256) ? msg_W1[(size_t)k * 256 + j]
                                : msg_W1[(size_t)(128 + k) * 256 + (j - 256)];
            WpqT[t] = f2bf(v);
            return;
        }
        t -= 65536;
        if (t < 512) { bias_pq[t] = (t < 256) ? msg_b1[t] : 0.f; return; }
        t -= 512;
        if (t < 65536) {             // WmsgT[256][256]
            int j = t >> 8, k = t & 255;
            WmsgT[t] = f2bf(msg_W2[(size_t)k * 256 + j]);
            return;
        }
        t -= 65536;
        if (t < 131072) {            // Wu1T[256][512]
            int j = t >> 9, k = t & 511;
            Wu1T[t] = f2bf(upd_W1[(size_t)k * 256 + j]);
            return;
        }
        t -= 131072;
        if (t < 32768) {             // Wu2T[128][256]
            int j = t >> 8, k = t & 255;
            Wu2T[t] = f2bf(upd_W2[(size_t)k * 128 + j]);
        }
    }
}

// ---------------------------------------------------------------------------
// k_vt: VT[d][aoff[b] + (n - offs[b])] = bf16(x[n][d]) — per-batch 8-aligned
// key spans so attention PV B-frags are 16B-aligned b128 global loads.
// ---------------------------------------------------------------------------
__global__ __launch_bounds__(256) void k_vt(
    const float* __restrict__ x1, const float* __restrict__ x2,
    const int* __restrict__ offs1, const int* __restrict__ aoff1,
    const int* __restrict__ offs2, const int* __restrict__ aoff2,
    short* __restrict__ VT1, short* __restrict__ VT2, int N)
{
    __shared__ float xs[64][132];
    int nb = N >> 6;
    int bid = blockIdx.x;
    const float* x; const int* offs; const int* aoff; short* VT;
    if (bid < nb) { x = x1; offs = offs1; aoff = aoff1; VT = VT1; }
    else { bid -= nb; x = x2; offs = offs2; aoff = aoff2; VT = VT2; }
    int n0 = bid * 64;
    int t = threadIdx.x;
    for (int idx = t; idx < 64 * 32; idx += 256) {
        int r = idx >> 5, c4 = idx & 31;
        float4 v = *(const float4*)&x[(size_t)(n0 + r) * DFEAT + c4 * 4];
        *(float4*)&xs[r][c4 * 4] = v;
    }
    __syncthreads();
    int lane = t & 63, wv = t >> 6;
    int n = n0 + lane;
    int lo = 0, hi = 64;
    while (lo + 1 < hi) { int mid = (lo + hi) >> 1; if (offs[mid] <= n) lo = mid; else hi = mid; }
    int dst = aoff[lo] + (n - offs[lo]);
    size_t nvt = (size_t)N + 1024;
    for (int d = wv; d < DFEAT; d += 4)
        VT[(size_t)d * nvt + dst] = f2bf(xs[lane][d]);
}

// ---------------------------------------------------------------------------
// CSR build: scan + scatter.
// ---------------------------------------------------------------------------
__global__ __launch_bounds__(256) void k_scan(const int* __restrict__ deg1,
                                              const int* __restrict__ deg2, int N,
                                              int* __restrict__ offs1, int* __restrict__ cur1,
                                              int* __restrict__ offs2, int* __restrict__ cur2) {
    const int* deg = blockIdx.x ? deg2 : deg1;
    int* offs = blockIdx.x ? offs2 : offs1;
    int* cur  = blockIdx.x ? cur2  : cur1;
    int t = threadIdx.x;
    int base = t * 32;
    int vals[32];
    int run = 0;
    #pragma unroll
    for (int i = 0; i < 32; ++i) { vals[i] = run; run += deg[base + i]; }
    __shared__ int tot[256];
    tot[t] = run;
    __syncthreads();
    for (int off = 1; off < 256; off <<= 1) {
        int v = (t >= off) ? tot[t - off] : 0;
        __syncthreads();
        tot[t] += v;
        __syncthreads();
    }
    int prefix = (t == 0) ? 0 : tot[t - 1];
    #pragma unroll
    for (int i = 0; i < 32; ++i) {
        int o = prefix + vals[i];
        offs[base + i] = o;
        cur[base + i] = o;
    }
    if (t == 255) offs[N] = tot[255];
}

__global__ __launch_bounds__(256) void k_scatter(const int* __restrict__ ei1,
                                                 const int* __restrict__ ei2, int E,
                                                 int* __restrict__ cur1, int* __restrict__ srcb1,
                                                 int* __restrict__ cur2, int* __restrict__ srcb2) {
    int t = blockIdx.x * 256 + threadIdx.x;
    if (t < E) {
        int tgt = ei1[t], src = ei1[E + t];
        srcb1[atomicAdd(cur1 + tgt, 1)] = src;
    } else if (t < 2 * E) {
        int e = t - E;
        int tgt = ei2[e], src = ei2[E + e];
        srcb2[atomicAdd(cur2 + tgt, 1)] = src;
    }
}

// ---------------------------------------------------------------------------
// MFMA GEMM: PQ_bf16[N][512] = x_bf(U cols 384..511) @ Wpq + bias.
// ---------------------------------------------------------------------------
__global__ __launch_bounds__(256) void k_pq_mfma(const short* __restrict__ U1,
                                                 const short* __restrict__ U2,
                                                 const short* __restrict__ WpqT,
                                                 const float* __restrict__ bias,
                                                 short* __restrict__ PQ1,
                                                 short* __restrict__ PQ2, int nblk) {
    int blk = blockIdx.x;
    const short* A; short* C;
    if (blk < nblk) { A = U1; C = PQ1; } else { A = U2; C = PQ2; blk -= nblk; }
    int w = threadIdx.x >> 6, l = threadIdx.x & 63;
    int row0 = blk * 32 + (w & 1) * 16;
    int ct0 = (w >> 1) * 16;
    int lm = l & 15, kg = (l >> 4) * 8;
    const short* Ar = A + (size_t)(row0 + lm) * 512 + 384 + kg;
    short8b a[4];
    #pragma unroll
    for (int ks = 0; ks < 4; ++ks) a[ks] = *(const short8b*)(Ar + ks * 32);
    for (int ct = ct0; ct < ct0 + 16; ++ct) {
        f32x4 acc = {0.f, 0.f, 0.f, 0.f};
        const short* Br = WpqT + (size_t)(ct * 16 + lm) * 128 + kg;
        #pragma unroll
        for (int ks = 0; ks < 4; ++ks) {
            short8b b = *(const short8b*)(Br + ks * 32);
            acc = __builtin_amdgcn_mfma_f32_16x16x32_bf16(a[ks], b, acc, 0, 0, 0);
        }
        int col = ct * 16 + lm;
        float bv = bias[col];
        #pragma unroll
        for (int j = 0; j < 4; ++j) {
            int r = row0 + (l >> 4) * 4 + j;
            C[(size_t)r * 512 + col] = f2bf(acc[j] + bv);
        }
    }
}

// ---------------------------------------------------------------------------
// Gather-aggregate (bf16 PQ): Hag[n] = sum relu(P[src]+Q[n]). Both graphs.
// ---------------------------------------------------------------------------
__global__ __launch_bounds__(256) void k_aggr(const short* __restrict__ PQ1,
                                              const short* __restrict__ PQ2,
                                              const int* __restrict__ coffs1,
                                              const int* __restrict__ srcb1,
                                              const int* __restrict__ coffs2,
                                              const int* __restrict__ srcb2,
                                              short* __restrict__ Hag1,
                                              short* __restrict__ Hag2, int N) {
    int gw = (blockIdx.x * 256 + threadIdx.x) >> 6;
    int lane = threadIdx.x & 63;
    const short* PQ; const int* offs; const int* srcb; short* Hag;
    if (gw < N) { PQ = PQ1; offs = coffs1; srcb = srcb1; Hag = Hag1; }
    else { gw -= N; if (gw >= N) return; PQ = PQ2; offs = coffs2; srcb = srcb2; Hag = Hag2; }
    short4b q4 = *(const short4b*)(PQ + (size_t)gw * 512 + 256 + lane * 4);
    float qx = bf2f(q4.x), qy = bf2f(q4.y), qz = bf2f(q4.z), qw = bf2f(q4.w);
    int e0 = offs[gw], e1 = offs[gw + 1];
    float ax = 0.f, ay = 0.f, az = 0.f, aw = 0.f;
    int e = e0;
    for (; e + 1 < e1; e += 2) {
        int s0 = srcb[e], s1 = srcb[e + 1];
        short4b pa = *(const short4b*)(PQ + (size_t)s0 * 512 + lane * 4);
        short4b pb = *(const short4b*)(PQ + (size_t)s1 * 512 + lane * 4);
        ax += fmaxf(bf2f(pa.x) + qx, 0.f) + fmaxf(bf2f(pb.x) + qx, 0.f);
        ay += fmaxf(bf2f(pa.y) + qy, 0.f) + fmaxf(bf2f(pb.y) + qy, 0.f);
        az += fmaxf(bf2f(pa.z) + qz, 0.f) + fmaxf(bf2f(pb.z) + qz, 0.f);
        aw += fmaxf(bf2f(pa.w) + qw, 0.f) + fmaxf(bf2f(pb.w) + qw, 0.f);
    }
    if (e < e1) {
        int s0 = srcb[e];
        short4b pa = *(const short4b*)(PQ + (size_t)s0 * 512 + lane * 4);
        ax += fmaxf(bf2f(pa.x) + qx, 0.f);
        ay += fmaxf(bf2f(pa.y) + qy, 0.f);
        az += fmaxf(bf2f(pa.z) + qz, 0.f);
        aw += fmaxf(bf2f(pa.w) + qw, 0.f);
    }
    short4b o;
    o.x = f2bf(ax); o.y = f2bf(ay); o.z = f2bf(az); o.w = f2bf(aw);
    *(short4b*)(Hag + (size_t)gw * HDIM + lane * 4) = o;
}

// ---------------------------------------------------------------------------
// MFMA GEMM: msg = Hag_bf @ msg_W2 + deg*b2 -> bf16 into U cols 0..255.
// ---------------------------------------------------------------------------
__global__ __launch_bounds__(256) void k_msg_mfma(const short* __restrict__ Hag1,
                                                  const short* __restrict__ Hag2,
                                                  const short* __restrict__ WmsgT,
                                                  const float* __restrict__ b2,
                                                  const int* __restrict__ deg1,
                                                  const int* __restrict__ deg2,
                                                  short* __restrict__ U1,
                                                  short* __restrict__ U2, int nblk) {
    int blk = blockIdx.x;
    const short* A; short* U; const int* deg;
    if (blk < nblk) { A = Hag1; U = U1; deg = deg1; }
    else { A = Hag2; U = U2; deg = deg2; blk -= nblk; }
    int w = threadIdx.x >> 6, l = threadIdx.x & 63;
    int row0 = blk * 32 + (w & 1) * 16;
    int ct0 = (w >> 1) * 8;
    int lm = l & 15, kg = (l >> 4) * 8;
    const short* Ar = A + (size_t)(row0 + lm) * 256 + kg;
    short8b a[8];
    #pragma unroll
    for (int ks = 0; ks < 8; ++ks) a[ks] = *(const short8b*)(Ar + ks * 32);
    float dg[4];
    #pragma unroll
    for (int j = 0; j < 4; ++j) dg[j] = (float)deg[row0 + (l >> 4) * 4 + j];
    for (int ct = ct0; ct < ct0 + 8; ++ct) {
        f32x4 acc = {0.f, 0.f, 0.f, 0.f};
        const short* Br = WmsgT + (size_t)(ct * 16 + lm) * 256 + kg;
        #pragma unroll
        for (int ks = 0; ks < 8; ++ks) {
            short8b b = *(const short8b*)(Br + ks * 32);
            acc = __builtin_amdgcn_mfma_f32_16x16x32_bf16(a[ks], b, acc, 0, 0, 0);
        }
        int col = ct * 16 + lm;
        float bv = b2[col];
        #pragma unroll
        for (int j = 0; j < 4; ++j) {
            int r = row0 + (l >> 4) * 4 + j;
            U[(size_t)r * 512 + col] = f2bf(acc[j] + dg[j] * bv);
        }
    }
}

// ---------------------------------------------------------------------------
// MFMA flash attention (v4: 1-wave blocks, no barriers, all frags global).
// grid (64 batches, 24 q-tiles, 2 dirs); 64 threads.
// Split-bf16 QK^T (Qh*Kh + Ql*Kh + Qh*Kl); K-frags from U/Xlo (row-major,
// aligned); PV B-frags from VT (per-batch 8-aligned spans); P transposed
// via wave-private LDS (in-order LDS pipe -> no syncs needed).
// ---------------------------------------------------------------------------
__global__ __launch_bounds__(64) void k_attn(
    const float* __restrict__ x1, const float* __restrict__ x2,
    const short* __restrict__ Xlo1, const short* __restrict__ Xlo2,
    const int* __restrict__ offs1, const int* __restrict__ offs2,
    const int* __restrict__ aoff1, const int* __restrict__ aoff2,
    const short* __restrict__ VT1, const short* __restrict__ VT2,
    short* __restrict__ U1, short* __restrict__ U2, int N)
{
    alignas(16) __shared__ short Pl[16][SVP];
    int b = blockIdx.x, g = blockIdx.z;
    const float* xq   = g ? x2 : x1;
    const short* Uq   = g ? U2 : U1;
    const short* Loq  = g ? Xlo2 : Xlo1;
    const short* Uk   = g ? U1 : U2;
    const short* Lok  = g ? Xlo1 : Xlo2;
    const short* VTk  = g ? VT1 : VT2;
    const int* offsq  = g ? offs2 : offs1;
    const int* offsk  = g ? offs1 : offs2;
    const int* aoffk  = g ? aoff1 : aoff2;
    short* Uo = g ? U2 : U1;
    int q0 = offsq[b], q1 = offsq[b + 1];
    int k0 = offsk[b], k1 = offsk[b + 1];
    int a0 = aoffk[b];
    int nk = k1 - k0;
    int r0 = q0 + blockIdx.y * 16;
    if (r0 >= q1 || nk <= 0) return;
    int l = threadIdx.x, lm = l & 15, gq = l >> 4;
    size_t nvt = (size_t)N + 1024;

    // Q frags (hi/lo), rows clamped
    int arow = min(r0 + lm, q1 - 1);
    const short* Aq  = Uq + (size_t)arow * 512 + 384 + gq * 8;
    const short* Alo = Loq + (size_t)arow * DFEAT + gq * 8;
    short8b ah[4], al[4];
    #pragma unroll
    for (int ks = 0; ks < 4; ++ks) {
        ah[ks] = *(const short8b*)(Aq + ks * 32);
        al[ks] = *(const short8b*)(Alo + ks * 32);
    }
    float m[4], lsum[4];
    f32x4 O[8];
    #pragma unroll
    for (int j = 0; j < 4; ++j) { m[j] = -1e30f; lsum[j] = 0.f; }
    #pragma unroll
    for (int dt = 0; dt < 8; ++dt) O[dt] = (f32x4){0.f, 0.f, 0.f, 0.f};

    for (int t0 = 0; t0 < nk; t0 += ANC) {
        int ktlen = min(ANC, nk - t0);
        // --- QK^T (split), K-frags from global ---
        f32x4 s[ANT];
        #pragma unroll
        for (int kt = 0; kt < ANT; ++kt) s[kt] = (f32x4){0.f, 0.f, 0.f, 0.f};
        #pragma unroll
        for (int kt = 0; kt < ANT; ++kt) {
            if (kt * 16 < ktlen) {
                int krow = min(k0 + t0 + kt * 16 + lm, k1 - 1);
                const short* Bh = Uk + (size_t)krow * 512 + 384 + gq * 8;
                const short* Bl = Lok + (size_t)krow * DFEAT + gq * 8;
                #pragma unroll
                for (int ks = 0; ks < 4; ++ks) {
                    short8b bh = *(const short8b*)(Bh + ks * 32);
                    short8b bl = *(const short8b*)(Bl + ks * 32);
                    s[kt] = __builtin_amdgcn_mfma_f32_16x16x32_bf16(ah[ks], bh, s[kt], 0, 0, 0);
                    s[kt] = __builtin_amdgcn_mfma_f32_16x16x32_bf16(al[ks], bh, s[kt], 0, 0, 0);
                    s[kt] = __builtin_amdgcn_mfma_f32_16x16x32_bf16(ah[ks], bl, s[kt], 0, 0, 0);
                }
            }
        }
        // --- masked online softmax (row=gq*4+j, col=kt*16+lm) ---
        float tm[4] = {-1e30f, -1e30f, -1e30f, -1e30f};
        #pragma unroll
        for (int kt = 0; kt < ANT; ++kt) {
            bool v = (kt * 16 + lm) < ktlen;
            #pragma unroll
            for (int j = 0; j < 4; ++j) {
                float sv = v ? s[kt][j] : -1e30f;
                s[kt][j] = sv;
                tm[j] = fmaxf(tm[j], sv);
            }
        }
        #pragma unroll
        for (int j = 0; j < 4; ++j) {
            #pragma unroll
            for (int off = 8; off; off >>= 1) tm[j] = fmaxf(tm[j], __shfl_xor(tm[j], off));
        }
        float sc[4], ps[4];
        #pragma unroll
        for (int j = 0; j < 4; ++j) {
            float nm = fmaxf(m[j], tm[j]);
            sc[j] = __expf(m[j] - nm);
            m[j] = nm;
            ps[j] = 0.f;
        }
        #pragma unroll
        for (int kt = 0; kt < ANT; ++kt) {
            #pragma unroll
            for (int j = 0; j < 4; ++j) {
                float pv = __expf(s[kt][j] - m[j]);
                ps[j] += pv;
                Pl[gq * 4 + j][kt * 16 + lm] = f2bf(pv);
            }
        }
        #pragma unroll
        for (int j = 0; j < 4; ++j) {
            #pragma unroll
            for (int off = 8; off; off >>= 1) ps[j] += __shfl_xor(ps[j], off);
            lsum[j] = lsum[j] * sc[j] + ps[j];
        }
        #pragma unroll
        for (int dt = 0; dt < 8; ++dt)
            #pragma unroll
            for (int j = 0; j < 4; ++j) O[dt][j] *= sc[j];

        // --- PV: O += P @ V, B-frags from VT global (aligned spans) ---
        int nks = (ktlen + 31) >> 5;
        for (int ks = 0; ks < nks; ++ks) {
            short8b a = *(const short8b*)&Pl[lm][ks * 32 + gq * 8];
            size_t kb = (size_t)(a0 + t0 + ks * 32 + gq * 8);
            #pragma unroll
            for (int dt = 0; dt < 8; ++dt) {
                const short* vb = VTk + (size_t)(dt * 16 + lm) * nvt + kb;
                short8b bv = *(const short8b*)vb;
                O[dt] = __builtin_amdgcn_mfma_f32_16x16x32_bf16(a, bv, O[dt], 0, 0, 0);
            }
        }
    }
    // --- write attn = x - O/l into U cols 256..383 ---
    float inv[4];
    #pragma unroll
    for (int j = 0; j < 4; ++j) inv[j] = 1.0f / lsum[j];
    #pragma unroll
    for (int dt = 0; dt < 8; ++dt) {
        #pragma unroll
        for (int j = 0; j < 4; ++j) {
            int qrow = r0 + gq * 4 + j;
            if (qrow < q1) {
                int d = dt * 16 + lm;
                float xv = xq[(size_t)qrow * DFEAT + d];
                Uo[(size_t)qrow * 512 + 256 + d] = f2bf(xv - O[dt][j] * inv[j]);
            }
        }
    }
}

// ---------------------------------------------------------------------------
// MFMA fused update: out = x + relu(U@Wu1 + b1) @ Wu2 + b2.
// ---------------------------------------------------------------------------
__global__ __launch_bounds__(256) void k_upd_mfma(const short* __restrict__ U1,
                                                  const short* __restrict__ U2,
                                                  const float* __restrict__ x1,
                                                  const float* __restrict__ x2,
                                                  const short* __restrict__ Wu1T,
                                                  const short* __restrict__ Wu2T,
                                                  const float* __restrict__ b1,
                                                  const float* __restrict__ b2,
                                                  float* __restrict__ out1,
                                                  float* __restrict__ out2, int nblk) {
    __shared__ short Hs[32][264];
    int blk = blockIdx.x;
    const short* Up; const float* x; float* out;
    if (blk < nblk) { Up = U1; x = x1; out = out1; }
    else { Up = U2; x = x2; out = out2; blk -= nblk; }
    int w = threadIdx.x >> 6, l = threadIdx.x & 63;
    int rw = (w & 1) * 16;
    int row0 = blk * 32 + rw;
    int lm = l & 15, kg = (l >> 4) * 8;

    int ct0 = (w >> 1) * 8;
    const short* Ar = Up + (size_t)(row0 + lm) * 512 + kg;
    short8b a[16];
    #pragma unroll
    for (int ks = 0; ks < 16; ++ks) a[ks] = *(const short8b*)(Ar + ks * 32);
    for (int ct = ct0; ct < ct0 + 8; ++ct) {
        f32x4 acc = {0.f, 0.f, 0.f, 0.f};
        const short* Br = Wu1T + (size_t)(ct * 16 + lm) * 512 + kg;
        #pragma unroll
        for (int ks = 0; ks < 16; ++ks) {
            short8b b = *(const short8b*)(Br + ks * 32);
            acc = __builtin_amdgcn_mfma_f32_16x16x32_bf16(a[ks], b, acc, 0, 0, 0);
        }
        int col = ct * 16 + lm;
        float bv = b1[col];
        #pragma unroll
        for (int j = 0; j < 4; ++j) {
            int r = rw + (l >> 4) * 4 + j;
            Hs[r][col] = f2bf(fmaxf(acc[j] + bv, 0.f));
        }
    }
    __syncthreads();

    int ct20 = (w >> 1) * 4;
    short8b a2[8];
    #pragma unroll
    for (int ks = 0; ks < 8; ++ks)
        a2[ks] = *(const short8b*)&Hs[rw + lm][ks * 32 + kg];
    for (int ct = ct20; ct < ct20 + 4; ++ct) {
        f32x4 acc = {0.f, 0.f, 0.f, 0.f};
        const short* Br = Wu2T + (size_t)(ct * 16 + lm) * 256 + kg;
        #pragma unroll
        for (int ks = 0; ks < 8; ++ks) {
            short8b b = *(const short8b*)(Br + ks * 32);
            acc = __builtin_amdgcn_mfma_f32_16x16x32_bf16(a2[ks], b, acc, 0, 0, 0);
        }
        int col = ct * 16 + lm;
        float bv = b2[col];
        #pragma unroll
        for (int j = 0; j < 4; ++j) {
            int r = row0 + (l >> 4) * 4 + j;
            out[(size_t)r * DFEAT + col] = x[(size_t)r * DFEAT + col] + acc[j] + bv;
        }
    }
}

// ---------------------------------------------------------------------------
extern "C" void kernel_launch(void* const* d_in, const int* in_sizes, int n_in,
                              void* d_out, int out_size, void* d_ws, size_t ws_size,
                              hipStream_t stream) {
    const float* x1     = (const float*)d_in[0];
    const int*   ei1    = (const int*)d_in[1];
    const int*   batch1 = (const int*)d_in[2];
    const float* x2     = (const float*)d_in[3];
    const int*   ei2    = (const int*)d_in[4];
    const int*   batch2 = (const int*)d_in[5];
    const float* msg_W1 = (const float*)d_in[6];
    const float* msg_b1 = (const float*)d_in[7];
    const float* msg_W2 = (const float*)d_in[8];
    const float* msg_b2 = (const float*)d_in[9];
    const float* upd_W1 = (const float*)d_in[10];
    const float* upd_b1 = (const float*)d_in[11];
    const float* upd_W2 = (const float*)d_in[12];
    const float* upd_b2 = (const float*)d_in[13];

    const int N = in_sizes[0] / DFEAT;   // 8192
    const int E = in_sizes[1] / 2;       // 131072

    char* base = (char*)d_ws;
    int* offs1   = (int*)base;                 // 128
    int* offs2   = offs1 + 128;                // 128
    int* aoff1   = offs2 + 128;                // 128
    int* aoff2   = aoff1 + 128;                // 128
    int* deg1    = aoff2 + 128;                // N
    int* deg2    = deg1 + N;                   // N
    int* coffs1  = deg2 + N;                   // N+64
    int* coffs2  = coffs1 + (N + 64);          // N+64
    int* cur1    = coffs2 + (N + 64);          // N
    int* cur2    = cur1 + N;                   // N
    int* srcb1   = cur2 + N;                   // E
    int* srcb2   = srcb1 + E;                  // E
    float* bias_pq = (float*)(srcb2 + E);      // 512
    short* S = (short*)(bias_pq + 512);
    size_t N512 = (size_t)N * 512;
    size_t NVT = (size_t)N + 1024;
    short* PQ1   = S;                          // N*512 bf16
    short* PQ2   = PQ1 + N512;
    short* Hag1  = PQ2 + N512;                 // N*256
    short* Hag2  = Hag1 + (size_t)N * 256;
    short* U1    = Hag2 + (size_t)N * 256;     // N*512
    short* U2    = U1 + N512;
    short* Xlo1  = U2 + N512;                  // N*128
    short* Xlo2  = Xlo1 + (size_t)N * 128;
    short* VT1   = Xlo2 + (size_t)N * 128;     // 128*(N+1024)
    short* VT2   = VT1 + 128 * NVT;
    short* WpqT  = VT2 + 128 * NVT;            // 512*128
    short* WmsgT = WpqT + 65536;               // 256*256
    short* Wu1T  = WmsgT + 65536;              // 256*512
    short* Wu2T  = Wu1T + 131072;              // 128*256

    hipMemsetAsync(deg1, 0, 2 * (size_t)N * sizeof(int), stream);

    int hb = (2 * E + 255) / 256;
    int xb = N / 4;
    int prep_blocks = 1 + hb + xb + 1154;
    k_prep<<<prep_blocks, 256, 0, stream>>>(batch1, batch2, ei1, ei2, x1, x2,
                                            msg_W1, msg_b1, msg_W2, upd_W1, upd_W2,
                                            N, E, offs1, offs2, aoff1, aoff2,
                                            deg1, deg2, U1, U2, Xlo1, Xlo2,
                                            WpqT, bias_pq, WmsgT, Wu1T, Wu2T);

    k_vt<<<2 * (N / 64), 256, 0, stream>>>(x1, x2, offs1, aoff1, offs2, aoff2,
                                           VT1, VT2, N);

    k_scan<<<2, 256, 0, stream>>>(deg1, deg2, N, coffs1, cur1, coffs2, cur2);
    k_scatter<<<(2 * E + 255) / 256, 256, 0, stream>>>(ei1, ei2, E, cur1, srcb1, cur2, srcb2);

    int nblk = N / 32;   // 256
    k_pq_mfma<<<2 * nblk, 256, 0, stream>>>(U1, U2, WpqT, bias_pq, PQ1, PQ2, nblk);

    k_aggr<<<2 * (N / 4), 256, 0, stream>>>(PQ1, PQ2, coffs1, srcb1, coffs2, srcb2,
                                            Hag1, Hag2, N);

    k_msg_mfma<<<2 * nblk, 256, 0, stream>>>(Hag1, Hag2, WmsgT, msg_b2,
                                             deg1, deg2, U1, U2, nblk);

    k_attn<<<dim3(64, 24, 2), 64, 0, stream>>>(x1, x2, Xlo1, Xlo2, offs1, offs2,
                                               aoff1, aoff2, VT1, VT2, U1, U2, N);

    float* out1 = (float*)d_out;
    float* out2 = out1 + (size_t)N * DFEAT;
    k_upd_mfma<<<2 * nblk, 256, 0, stream>>>(U1, U2, x1, x2, Wu1T, Wu2T,
                                             upd_b1, upd_b2, out1, out2, nblk);
}